// Round 7
// baseline (93.822 us; speedup 1.0000x reference)
//
#include <hip/hip_runtime.h>

typedef __attribute__((ext_vector_type(4))) float  f32x4;
typedef __attribute__((ext_vector_type(8))) short  bf16x8;

typedef __attribute__((address_space(3))) void lds_void_t;
typedef __attribute__((address_space(1))) void g_void_t;

#define S_LEN  2048
#define DMODEL 1024
#define NHEAD  16
#define HDIM   64
#define NBLK   128   // S/16 blocks per sequence
#define BATCH  2
#define KT     64    // keys per attn inner tile
#define VP     72    // padded row stride (shorts, multiple of 8 for b128 alignment)

__device__ __forceinline__ short f2bf(float f) {
  union { float f; unsigned u; } v; v.f = f;
  unsigned r = v.u + 0x7fffu + ((v.u >> 16) & 1u);
  return (short)(r >> 16);
}

// ---------------- merged fp32 -> bf16 convert: x + 4 weight matrices ----------------
__global__ __launch_bounds__(256) void cvt_all_kernel(
    const float* __restrict__ x,  const float* __restrict__ wq,
    const float* __restrict__ wk, const float* __restrict__ wv,
    const float* __restrict__ wo,
    short* __restrict__ xb,  short* __restrict__ wqb,
    short* __restrict__ wkb, short* __restrict__ wvb,
    short* __restrict__ wob) {
  const long i = ((long)blockIdx.x * 256 + threadIdx.x) * 8;
  const float* s; short* d; long off;
  if (i < 4194304L)      { s = x;  d = xb;  off = i; }
  else if (i < 5242880L) { s = wq; d = wqb; off = i - 4194304L; }
  else if (i < 6291456L) { s = wk; d = wkb; off = i - 5242880L; }
  else if (i < 7340032L) { s = wv; d = wvb; off = i - 6291456L; }
  else                   { s = wo; d = wob; off = i - 7340032L; }
  f32x4 a = *(const f32x4*)(s + off);
  f32x4 b = *(const f32x4*)(s + off + 4);
  bf16x8 o;
  o[0]=f2bf(a[0]); o[1]=f2bf(a[1]); o[2]=f2bf(a[2]); o[3]=f2bf(a[3]);
  o[4]=f2bf(b[0]); o[5]=f2bf(b[1]); o[6]=f2bf(b[2]); o[7]=f2bf(b[3]);
  *(bf16x8*)(d + off) = o;
}

// ---------------- QKV GEMM: 256x192 tile, BK=64, 8 waves, counted-vmcnt pipeline ----------------
__global__ __launch_bounds__(512, 2) void gemm8_kernel(
    const short* __restrict__ A,
    const short* __restrict__ W0, const short* __restrict__ W1, const short* __restrict__ W2,
    const int* __restrict__ slot_map,
    short* __restrict__ qbuf, short* __restrict__ kcache, short* __restrict__ vcache)
{
  extern __shared__ short smem[];   // 57344 shorts = 112 KiB

  const int m0 = blockIdx.x * 256;
  const int n0 = blockIdx.y * 192;
  const short* Ag = A + (size_t)m0 * DMODEL;

  const int tid  = threadIdx.x;
  const int wave = tid >> 6, lane = tid & 63;
  const int l15 = lane & 15, lg = lane >> 4;
  const int wr = wave >> 2, wc = wave & 3;   // wave tile 128 x 48
  const int swz = l15 & 7;

  short* const A0s = smem;           // [256][64]
  short* const B0s = smem + 16384;   // [192][64]
  short* const A1s = smem + 28672;
  short* const B1s = smem + 45056;

  f32x4 acc[8][3];
#pragma unroll
  for (int m = 0; m < 8; m++)
#pragma unroll
    for (int n = 0; n < 3; n++) acc[m][n] = (f32x4)0.f;

#define STAGE_A(DST, K0, P) {                                                              \
    const int gidx = (P) * 512 + tid;                                                      \
    const int r = gidx >> 3;                                                               \
    const int cs = (gidx & 7) ^ (r & 7);                                                   \
    __builtin_amdgcn_global_load_lds((g_void_t*)(Ag + (size_t)r * DMODEL + (K0) + cs * 8), \
        (lds_void_t*)((DST) + ((P) * 512 + wave * 64) * 8), 16, 0, 0); }

#define STAGE_B(DST, K0, P) {                                                              \
    const int gidx = (P) * 512 + tid;                                                      \
    const int r = gidx >> 3;                                                               \
    const int grow = n0 + r;                                                               \
    const short* wb = (grow < 1024) ? W0 : (grow < 2048) ? W1 : W2;                        \
    const int cs = (gidx & 7) ^ (r & 7);                                                   \
    __builtin_amdgcn_global_load_lds((g_void_t*)(wb + (size_t)(grow & 1023) * DMODEL + (K0) + cs * 8), \
        (lds_void_t*)((DST) + ((P) * 512 + wave * 64) * 8), 16, 0, 0); }

#define PHASE_BAR() do {                                        \
    asm volatile("" ::: "memory");                              \
    __builtin_amdgcn_s_barrier();                               \
    asm volatile("" ::: "memory");                              \
  } while (0)

#define PHASE_READ_A(BUF, Q)                                                               \
    _Pragma("unroll") for (int mi = 0; mi < 2; ++mi) {                                     \
      const int row = wr * 128 + ((Q) * 2 + mi) * 16 + l15;                                \
      _Pragma("unroll") for (int ks = 0; ks < 2; ++ks)                                     \
        af[mi][ks] = *(const bf16x8*)((BUF) + row * 64 + (((ks * 4 + lg) ^ swz) << 3)); }

#define PHASE_MFMA(Q)                                                                      \
    __builtin_amdgcn_s_setprio(1);                                                         \
    _Pragma("unroll") for (int mi = 0; mi < 2; ++mi)                                       \
    _Pragma("unroll") for (int nt = 0; nt < 3; ++nt)                                       \
    _Pragma("unroll") for (int ks = 0; ks < 2; ++ks)                                       \
      acc[(Q) * 2 + mi][nt] = __builtin_amdgcn_mfma_f32_16x16x32_bf16(                     \
          af[mi][ks], bfr[nt][ks], acc[(Q) * 2 + mi][nt], 0, 0, 0);                        \
    __builtin_amdgcn_s_setprio(0);

  // ---- prologue: tile 0, one-time full drain ----
  STAGE_B(B0s, 0, 0); STAGE_B(B0s, 0, 1); STAGE_B(B0s, 0, 2);
  STAGE_A(A0s, 0, 0); STAGE_A(A0s, 0, 2); STAGE_A(A0s, 0, 1); STAGE_A(A0s, 0, 3);
  asm volatile("s_waitcnt vmcnt(0)" ::: "memory");
  __builtin_amdgcn_s_barrier();
  asm volatile("" ::: "memory");

  const int NT = DMODEL / 64;   // 16 K-tiles
  for (int t = 0; t < NT; ++t) {
    const bool stg = (t + 1 < NT);
    short* const Ac = (t & 1) ? A1s : A0s;
    short* const Bc = (t & 1) ? B1s : B0s;
    short* const An = (t & 1) ? A0s : A1s;
    short* const Bn = (t & 1) ? B0s : B1s;
    const int kn = (t + 1) * 64;

    bf16x8 af[2][2], bfr[3][2];

    // ---- P1: read B all + A m0,m1; stage B(t+1) x3 ----
#pragma unroll
    for (int nt = 0; nt < 3; ++nt) {
      const int row = wc * 48 + nt * 16 + l15;
#pragma unroll
      for (int ks = 0; ks < 2; ++ks)
        bfr[nt][ks] = *(const bf16x8*)(Bc + row * 64 + (((ks * 4 + lg) ^ swz) << 3));
    }
    PHASE_READ_A(Ac, 0);
    if (stg) { STAGE_B(Bn, kn, 0); STAGE_B(Bn, kn, 1); STAGE_B(Bn, kn, 2); }
    PHASE_BAR();
    PHASE_MFMA(0);
    PHASE_BAR();

    // ---- P2: read A m2,m3; stage A(t+1) op0,op2 ----
    PHASE_READ_A(Ac, 1);
    if (stg) { STAGE_A(An, kn, 0); STAGE_A(An, kn, 2); }
    PHASE_BAR();
    PHASE_MFMA(1);
    if (stg) { asm volatile("s_waitcnt vmcnt(6)" ::: "memory"); }
    else     { asm volatile("s_waitcnt vmcnt(1)" ::: "memory"); }
    PHASE_BAR();

    // ---- P3: read A m4,m5; stage A(t+1) op1 ----
    PHASE_READ_A(Ac, 2);
    if (stg) { STAGE_A(An, kn, 1); }
    PHASE_BAR();
    PHASE_MFMA(2);
    if (stg) { asm volatile("s_waitcnt vmcnt(6)" ::: "memory"); }
    else     { asm volatile("s_waitcnt vmcnt(0)" ::: "memory"); }
    PHASE_BAR();

    // ---- P4: read A m6,m7; stage A(t+1) op3 ----
    PHASE_READ_A(Ac, 3);
    if (stg) { STAGE_A(An, kn, 3); }
    PHASE_BAR();
    PHASE_MFMA(3);
    asm volatile("s_waitcnt vmcnt(2)" ::: "memory");   // retire B + A-op0/op2 of next tile
    PHASE_BAR();
  }
#undef STAGE_A
#undef STAGE_B
#undef PHASE_BAR
#undef PHASE_READ_A
#undef PHASE_MFMA

  // ---- epilogue: scatter to q / k / v ----
#pragma unroll
  for (int mf = 0; mf < 8; ++mf) {
    const int rowb = m0 + wr * 128 + mf * 16 + lg * 4;
#pragma unroll
    for (int r4 = 0; r4 < 4; ++r4) {
      const int row = rowb + r4;
      const int slot = slot_map[row];
#pragma unroll
      for (int nt = 0; nt < 3; ++nt) {
        const int col = n0 + wc * 48 + nt * 16 + l15;
        const short bv = f2bf(acc[mf][nt][r4]);
        if (col < DMODEL)
          qbuf[(size_t)row * DMODEL + col] = bv;
        else if (col < 2 * DMODEL)
          kcache[(size_t)slot * DMODEL + (col - DMODEL)] = bv;
        else
          vcache[(size_t)slot * DMODEL + (col - 2 * DMODEL)] = bv;
      }
    }
  }
}

// ---------------- out-proj GEMM: 64x128 tile, BK=64, 4 waves, counted-vmcnt dbuf ----------------
__global__ __launch_bounds__(256) void gemm1_kernel(
    const short* __restrict__ A, const short* __restrict__ W,
    float* __restrict__ outf)
{
  __shared__ short As[2][64 * 64];
  __shared__ short Bs[2][128 * 64];

  const int m0 = blockIdx.x * 64;
  const int n0 = blockIdx.y * 128;
  const short* Ag = A + (size_t)m0 * DMODEL;
  const short* Bg = W + (size_t)n0 * DMODEL;

  const int tid = threadIdx.x;
  const int wave = tid >> 6, lane = tid & 63;
  const int l15 = lane & 15, lg = lane >> 4;
  const int swz = l15 & 7;

  f32x4 acc[4][2];
#pragma unroll
  for (int m = 0; m < 4; m++)
#pragma unroll
    for (int n = 0; n < 2; n++) acc[m][n] = (f32x4)0.f;

#define STG1(BUF, K0) {                                                                    \
    _Pragma("unroll") for (int p = 0; p < 2; ++p) {                                        \
      const int u = p * 256 + tid; const int r = u >> 3; const int cs = (u & 7) ^ (r & 7); \
      __builtin_amdgcn_global_load_lds((g_void_t*)(Ag + (size_t)r * DMODEL + (K0) + cs * 8), \
          (lds_void_t*)(As[BUF] + (p * 256 + wave * 64) * 8), 16, 0, 0); }                 \
    _Pragma("unroll") for (int p = 0; p < 4; ++p) {                                        \
      const int u = p * 256 + tid; const int r = u >> 3; const int cs = (u & 7) ^ (r & 7); \
      __builtin_amdgcn_global_load_lds((g_void_t*)(Bg + (size_t)r * DMODEL + (K0) + cs * 8), \
          (lds_void_t*)(Bs[BUF] + (p * 256 + wave * 64) * 8), 16, 0, 0); } }

  STG1(0, 0);
  asm volatile("s_waitcnt vmcnt(0)" ::: "memory");
  __builtin_amdgcn_s_barrier();
  asm volatile("" ::: "memory");

  for (int t = 0; t < 16; ++t) {
    const int cur = t & 1;
    if (t + 1 < 16) {
      STG1(cur ^ 1, (t + 1) * 64);
      asm volatile("s_waitcnt vmcnt(6)" ::: "memory");   // retire tile t's 6; t+1's 6 stay in flight
    } else {
      asm volatile("s_waitcnt vmcnt(0)" ::: "memory");
    }
    asm volatile("" ::: "memory");
    __builtin_amdgcn_s_barrier();
    asm volatile("" ::: "memory");

    bf16x8 af[4][2], bfr[2][2];
#pragma unroll
    for (int m4 = 0; m4 < 4; ++m4) {
      const int row = m4 * 16 + l15;
#pragma unroll
      for (int ks = 0; ks < 2; ++ks)
        af[m4][ks] = *(const bf16x8*)(As[cur] + row * 64 + (((ks * 4 + lg) ^ swz) << 3));
    }
#pragma unroll
    for (int n2 = 0; n2 < 2; ++n2) {
      const int row = wave * 32 + n2 * 16 + l15;
#pragma unroll
      for (int ks = 0; ks < 2; ++ks)
        bfr[n2][ks] = *(const bf16x8*)(Bs[cur] + row * 64 + (((ks * 4 + lg) ^ swz) << 3));
    }
    __builtin_amdgcn_s_setprio(1);
#pragma unroll
    for (int m4 = 0; m4 < 4; ++m4)
#pragma unroll
      for (int n2 = 0; n2 < 2; ++n2)
#pragma unroll
        for (int ks = 0; ks < 2; ++ks)
          acc[m4][n2] = __builtin_amdgcn_mfma_f32_16x16x32_bf16(af[m4][ks], bfr[n2][ks], acc[m4][n2], 0, 0, 0);
    __builtin_amdgcn_s_setprio(0);

    asm volatile("" ::: "memory");
    __builtin_amdgcn_s_barrier();
    asm volatile("" ::: "memory");
  }
#undef STG1

#pragma unroll
  for (int m4 = 0; m4 < 4; ++m4) {
    const int rowb = m0 + m4 * 16 + lg * 4;
#pragma unroll
    for (int n2 = 0; n2 < 2; ++n2) {
      const int col = n0 + wave * 32 + n2 * 16 + l15;
#pragma unroll
      for (int r4 = 0; r4 < 4; ++r4)
        outf[(size_t)(rowb + r4) * DMODEL + col] = acc[m4][n2][r4];
    }
  }
}

// ---------------- sliding-window flash attention ----------------
// grid: (S/64, H, B), block 256 (4 waves), wave owns 16 q-rows.
// Occupancy lever: 1024 blocks (4/CU guaranteed, 6/CU by LDS ~27KB) vs round-6's 512x512t
// (2/CU hard cap, measured 27%). Fixed-shift softmax (p = exp(s-12)); reg-prefetched K/V
// (2 x 16B chunks/thread at 256 threads). Balance flip: bz==1 uses 31-bx so co-resident
// blocks pair light+heavy q-tiles.
__global__ __launch_bounds__(256, 4) void attn_kernel(
    const short* __restrict__ qbuf,
    const short* __restrict__ kcache, const short* __restrict__ vcache,
    const int* __restrict__ block_tables, const int* __restrict__ context_lens,
    const int* __restrict__ window_size,
    short* __restrict__ attn_out)
{
  __shared__ short Ks[KT * 64];        // XOR-swizzled rows (row stride 128B)
  __shared__ short Vt[HDIM * VP];      // V^T, key-rotated within rows, stride 72
  __shared__ short Pb[4 * 16 * VP];    // per-wave P tiles, stride 72

  const int b = blockIdx.z, h = blockIdx.y;
  const int bx = (b & 1) ? ((int)gridDim.x - 1 - (int)blockIdx.x) : (int)blockIdx.x;
  const int q0 = bx * 64;
  const int ctx = context_lens[b];
  const int ws  = window_size[0];
  const int* bt = block_tables + b * NBLK;

  const int tid  = threadIdx.x;
  const int wave = tid >> 6, lane = tid & 63;
  const int l15 = lane & 15, lg = lane >> 4;
  const int qw = q0 + wave * 16;       // this wave's 16 q-rows

  const short* qp = qbuf + ((size_t)(b * S_LEN + qw + l15)) * DMODEL + h * HDIM;
  const bf16x8 qf0 = *(const bf16x8*)(qp + lg * 8);
  const bf16x8 qf1 = *(const bf16x8*)(qp + 32 + lg * 8);

  f32x4 oacc[4];
  float lrow[4];
#pragma unroll
  for (int i = 0; i < 4; i++) { oacc[i] = (f32x4)0.f; lrow[i] = 0.f; }

  int kstart = q0 - ws + 1; if (kstart < 0) kstart = 0; kstart &= ~(KT - 1);
  int kend = q0 + 64; if (kend > ctx) kend = ctx;

  const int kr  = tid >> 2;            // staging: tile-local key 0..63
  const int dc0 = (tid & 3) << 4;      // staging: d-chunk base (two 8-elem chunks)
  const float rscale = 0.125f;         // HD^-0.5
  const float FM = 12.f;               // fixed softmax shift
  short* pw = Pb + wave * (16 * VP);
  const int swz = (l15 & 7) << 4;

  bf16x8 kreg0 = (bf16x8)0, kreg1 = (bf16x8)0, vreg0 = (bf16x8)0, vreg1 = (bf16x8)0;
  {
    const int key = kstart + kr;
    if (key < ctx) {
      const int slot = bt[key >> 4] * 16 + (key & 15);
      const short* kp = kcache + (size_t)slot * DMODEL + h * HDIM + dc0;
      const short* vp = vcache + (size_t)slot * DMODEL + h * HDIM + dc0;
      kreg0 = *(const bf16x8*)(kp);     kreg1 = *(const bf16x8*)(kp + 8);
      vreg0 = *(const bf16x8*)(vp);     vreg1 = *(const bf16x8*)(vp + 8);
    }
  }

  for (int kt = kstart; kt < kend; kt += KT) {
    __syncthreads();
    // ---- commit prefetched regs -> LDS ----
    *(bf16x8*)((char*)Ks + kr * 128 + (((dc0    ) * 2) ^ ((kr & 7) << 4))) = kreg0;
    *(bf16x8*)((char*)Ks + kr * 128 + (((dc0 + 8) * 2) ^ ((kr & 7) << 4))) = kreg1;
    {
      const int vc0 = (kr + dc0) & 63;
      const int vc1 = (kr + dc0 + 8) & 63;
#pragma unroll
      for (int j = 0; j < 8; j++) Vt[(dc0 + j) * VP + vc0]     = vreg0[j];
#pragma unroll
      for (int j = 0; j < 8; j++) Vt[(dc0 + 8 + j) * VP + vc1] = vreg1[j];
    }
    // ---- issue prefetch for next tile ----
    kreg0 = (bf16x8)0; kreg1 = (bf16x8)0; vreg0 = (bf16x8)0; vreg1 = (bf16x8)0;
    if (kt + KT < kend) {
      const int key = kt + KT + kr;
      if (key < ctx) {
        const int slot = bt[key >> 4] * 16 + (key & 15);
        const short* kp = kcache + (size_t)slot * DMODEL + h * HDIM + dc0;
        const short* vp = vcache + (size_t)slot * DMODEL + h * HDIM + dc0;
        kreg0 = *(const bf16x8*)(kp);     kreg1 = *(const bf16x8*)(kp + 8);
        vreg0 = *(const bf16x8*)(vp);     vreg1 = *(const bf16x8*)(vp + 8);
      }
    }
    __syncthreads();

    // per-wave dead-tile skip
    if ((kt > qw + 15) || (kt + (KT - 1) <= qw - ws)) continue;

    // ---- QK^T ----
    f32x4 sacc[4];
#pragma unroll
    for (int cg = 0; cg < 4; cg++) sacc[cg] = (f32x4)0.f;
#pragma unroll
    for (int cg = 0; cg < 4; cg++) {
      const char* kp = (const char*)Ks + (cg * 16 + l15) * 128;
      const bf16x8 k0 = *(const bf16x8*)(kp + ((lg * 16) ^ swz));
      const bf16x8 k1 = *(const bf16x8*)(kp + ((64 + lg * 16) ^ swz));
      sacc[cg] = __builtin_amdgcn_mfma_f32_16x16x32_bf16(qf0, k0, sacc[cg], 0, 0, 0);
      sacc[cg] = __builtin_amdgcn_mfma_f32_16x16x32_bf16(qf1, k1, sacc[cg], 0, 0, 0);
    }

    const bool fullvis = (kt + (KT - 1) <= qw) && (qw + 15 - kt < ws) && (kt + (KT - 1) < ctx);

    if (fullvis) {
#pragma unroll
      for (int r = 0; r < 4; r++) {
        const float e0 = __expf(sacc[0][r] * rscale - FM);
        const float e1 = __expf(sacc[1][r] * rscale - FM);
        const float e2 = __expf(sacc[2][r] * rscale - FM);
        const float e3 = __expf(sacc[3][r] * rscale - FM);
        lrow[r] += (e0 + e1) + (e2 + e3);
        short* pr = pw + (lg * 4 + r) * VP + l15;
        pr[0]  = f2bf(e0); pr[16] = f2bf(e1);
        pr[32] = f2bf(e2); pr[48] = f2bf(e3);
      }
    } else {
#pragma unroll
      for (int r = 0; r < 4; r++) {
        const int qrow = qw + lg * 4 + r;
        const int key0 = kt + l15;
        const bool ok0 = (key0      <= qrow) && (qrow - key0      < ws) && (key0      < ctx);
        const bool ok1 = (key0 + 16 <= qrow) && (qrow - key0 - 16 < ws) && (key0 + 16 < ctx);
        const bool ok2 = (key0 + 32 <= qrow) && (qrow - key0 - 32 < ws) && (key0 + 32 < ctx);
        const bool ok3 = (key0 + 48 <= qrow) && (qrow - key0 - 48 < ws) && (key0 + 48 < ctx);
        const float e0 = ok0 ? __expf(sacc[0][r] * rscale - FM) : 0.f;
        const float e1 = ok1 ? __expf(sacc[1][r] * rscale - FM) : 0.f;
        const float e2 = ok2 ? __expf(sacc[2][r] * rscale - FM) : 0.f;
        const float e3 = ok3 ? __expf(sacc[3][r] * rscale - FM) : 0.f;
        lrow[r] += (e0 + e1) + (e2 + e3);
        short* pr = pw + (lg * 4 + r) * VP + l15;
        pr[0]  = f2bf(e0); pr[16] = f2bf(e1);
        pr[32] = f2bf(e2); pr[48] = f2bf(e3);
      }
    }

    asm volatile("s_waitcnt lgkmcnt(0)" ::: "memory");

    // ---- PV : O(16x64) += P(16x64) * V(64x64) ----
#pragma unroll
    for (int kk = 0; kk < 2; kk++) {
      const bf16x8 pa = *(const bf16x8*)(pw + l15 * VP + kk * 32 + lg * 8);
#pragma unroll
      for (int dn = 0; dn < 4; dn++) {
        const int vrow = dn * 16 + l15;
        const int roff = (kk * 32 + lg * 8 + (vrow & ~7)) & 63;
        const bf16x8 vb = *(const bf16x8*)(Vt + vrow * VP + roff);
        oacc[dn] = __builtin_amdgcn_mfma_f32_16x16x32_bf16(pa, vb, oacc[dn], 0, 0, 0);
      }
    }
  }

#pragma unroll
  for (int r = 0; r < 4; r++) {
    float ls = lrow[r];
    ls += __shfl_xor(ls, 1); ls += __shfl_xor(ls, 2);
    ls += __shfl_xor(ls, 4); ls += __shfl_xor(ls, 8);
    const float inv = 1.f / fmaxf(ls, 1e-30f);
    const int row = qw + lg * 4 + r;
    short* op = attn_out + ((size_t)(b * S_LEN + row)) * DMODEL + h * HDIM;
#pragma unroll
    for (int dn = 0; dn < 4; dn++)
      op[dn * 16 + l15] = f2bf(oacc[dn][r] * inv);
  }
}

// ---------------- launch ----------------
extern "C" void kernel_launch(void* const* d_in, const int* in_sizes, int n_in,
                              void* d_out, int out_size, void* d_ws, size_t ws_size,
                              hipStream_t stream) {
  const float* x  = (const float*)d_in[0];
  const float* wq = (const float*)d_in[1];
  const float* wk = (const float*)d_in[2];
  const float* wv = (const float*)d_in[3];
  const float* wo = (const float*)d_in[4];
  const int* block_tables = (const int*)d_in[5];
  const int* slot_mapping = (const int*)d_in[6];
  const int* context_lens = (const int*)d_in[7];
  const int* window_size  = (const int*)d_in[8];
  float* out = (float*)d_out;

  char* ws = (char*)d_ws;
  short* xb     = (short*)(ws + (size_t)( 0 << 20));
  short* wqb    = (short*)(ws + (size_t)( 8 << 20));
  short* wkb    = (short*)(ws + (size_t)(10 << 20));
  short* wvb    = (short*)(ws + (size_t)(12 << 20));
  short* wob    = (short*)(ws + (size_t)(14 << 20));
  short* qbuf   = (short*)(ws + (size_t)(16 << 20));
  short* kcache = (short*)(ws + (size_t)(24 << 20));
  short* vcache = (short*)(ws + (size_t)(32 << 20));
  short* abuf   = (short*)(ws + (size_t)(40 << 20));

  // one-time: allow 112 KiB dynamic LDS for gemm8 (host state call, not stream-captured)
  static bool gemm8_init = [] {
    hipFuncSetAttribute(reinterpret_cast<const void*>(&gemm8_kernel),
                        hipFuncAttributeMaxDynamicSharedMemorySize, 114688);
    return true;
  }();
  (void)gemm8_init;

  cvt_all_kernel<<<4096, 256, 0, stream>>>(x, wq, wk, wv, wo, xb, wqb, wkb, wvb, wob);

  gemm8_kernel<<<dim3(16, 16), 512, 114688, stream>>>(xb, wqb, wkb, wvb, slot_mapping,
                                                      qbuf, kcache, vcache);

  attn_kernel<<<dim3(S_LEN / 64, NHEAD, BATCH), 256, 0, stream>>>(
      qbuf, kcache, vcache, block_tables, context_lens, window_size, abuf);

  gemm1_kernel<<<dim3(64, 8), 256, 0, stream>>>(abuf, wob, out);
}

// Round 8
// 89.818 us; speedup vs baseline: 1.0446x; 1.0446x over previous
//
#include <hip/hip_runtime.h>

typedef __attribute__((ext_vector_type(4))) float  f32x4;
typedef __attribute__((ext_vector_type(8))) short  bf16x8;

typedef __attribute__((address_space(3))) void lds_void_t;
typedef __attribute__((address_space(1))) void g_void_t;

#define S_LEN  2048
#define DMODEL 1024
#define NHEAD  16
#define HDIM   64
#define NBLK   128   // S/16 blocks per sequence
#define BATCH  2
#define KT     64    // keys per attn inner tile
#define VP     72    // padded row stride (shorts, multiple of 8 for b128 alignment)

__device__ __forceinline__ short f2bf(float f) {
  union { float f; unsigned u; } v; v.f = f;
  unsigned r = v.u + 0x7fffu + ((v.u >> 16) & 1u);
  return (short)(r >> 16);
}

// ---------------- merged fp32 -> bf16 convert: x + 4 weight matrices ----------------
__global__ __launch_bounds__(256) void cvt_all_kernel(
    const float* __restrict__ x,  const float* __restrict__ wq,
    const float* __restrict__ wk, const float* __restrict__ wv,
    const float* __restrict__ wo,
    short* __restrict__ xb,  short* __restrict__ wqb,
    short* __restrict__ wkb, short* __restrict__ wvb,
    short* __restrict__ wob) {
  const long i = ((long)blockIdx.x * 256 + threadIdx.x) * 8;
  const float* s; short* d; long off;
  if (i < 4194304L)      { s = x;  d = xb;  off = i; }
  else if (i < 5242880L) { s = wq; d = wqb; off = i - 4194304L; }
  else if (i < 6291456L) { s = wk; d = wkb; off = i - 5242880L; }
  else if (i < 7340032L) { s = wv; d = wvb; off = i - 6291456L; }
  else                   { s = wo; d = wob; off = i - 7340032L; }
  f32x4 a = *(const f32x4*)(s + off);
  f32x4 b = *(const f32x4*)(s + off + 4);
  bf16x8 o;
  o[0]=f2bf(a[0]); o[1]=f2bf(a[1]); o[2]=f2bf(a[2]); o[3]=f2bf(a[3]);
  o[4]=f2bf(b[0]); o[5]=f2bf(b[1]); o[6]=f2bf(b[2]); o[7]=f2bf(b[3]);
  *(bf16x8*)(d + off) = o;
}

// ---------------- QKV GEMM: 256x192 tile, BK=64, 8 waves, 2-wait counted-vmcnt pipeline ----
// Stage issue order (tile t stages t+1's buffer): P1: B0,B1,B2; P2: A0,A2; P3: A1,A3; P4: none.
// Consumption: t+1.P1 reads B + A0/A2 (5 oldest); t.P3/P4 read A1/A3 staged during t-1.P3.
// Wait ledger (2 waits/K-tile, never drain in steady state):
//   end-P2: vmcnt(5)  -> retires A1,A3 (issued in t-1.P3, ~4 phases old) before P3/P4 reads
//   end-P4: vmcnt(2)  -> retires B0-2,A0,A2 (>=3 phases old) before t+1.P1 reads
__global__ __launch_bounds__(512, 2) void gemm8_kernel(
    const short* __restrict__ A,
    const short* __restrict__ W0, const short* __restrict__ W1, const short* __restrict__ W2,
    const int* __restrict__ slot_map,
    short* __restrict__ qbuf, short* __restrict__ kcache, short* __restrict__ vcache)
{
  extern __shared__ short smem[];   // 57344 shorts = 112 KiB

  const int m0 = blockIdx.x * 256;
  const int n0 = blockIdx.y * 192;
  const short* Ag = A + (size_t)m0 * DMODEL;

  const int tid  = threadIdx.x;
  const int wave = tid >> 6, lane = tid & 63;
  const int l15 = lane & 15, lg = lane >> 4;
  const int wr = wave >> 2, wc = wave & 3;   // wave tile 128 x 48
  const int swz = l15 & 7;

  short* const A0s = smem;           // [256][64]
  short* const B0s = smem + 16384;   // [192][64]
  short* const A1s = smem + 28672;
  short* const B1s = smem + 45056;

  f32x4 acc[8][3];
#pragma unroll
  for (int m = 0; m < 8; m++)
#pragma unroll
    for (int n = 0; n < 3; n++) acc[m][n] = (f32x4)0.f;

#define STAGE_A(DST, K0, P) {                                                              \
    const int gidx = (P) * 512 + tid;                                                      \
    const int r = gidx >> 3;                                                               \
    const int cs = (gidx & 7) ^ (r & 7);                                                   \
    __builtin_amdgcn_global_load_lds((g_void_t*)(Ag + (size_t)r * DMODEL + (K0) + cs * 8), \
        (lds_void_t*)((DST) + ((P) * 512 + wave * 64) * 8), 16, 0, 0); }

#define STAGE_B(DST, K0, P) {                                                              \
    const int gidx = (P) * 512 + tid;                                                      \
    const int r = gidx >> 3;                                                               \
    const int grow = n0 + r;                                                               \
    const short* wb = (grow < 1024) ? W0 : (grow < 2048) ? W1 : W2;                        \
    const int cs = (gidx & 7) ^ (r & 7);                                                   \
    __builtin_amdgcn_global_load_lds((g_void_t*)(wb + (size_t)(grow & 1023) * DMODEL + (K0) + cs * 8), \
        (lds_void_t*)((DST) + ((P) * 512 + wave * 64) * 8), 16, 0, 0); }

#define PHASE_BAR() do {                                        \
    asm volatile("" ::: "memory");                              \
    __builtin_amdgcn_s_barrier();                               \
    asm volatile("" ::: "memory");                              \
  } while (0)

#define PHASE_READ_A(BUF, Q)                                                               \
    _Pragma("unroll") for (int mi = 0; mi < 2; ++mi) {                                     \
      const int row = wr * 128 + ((Q) * 2 + mi) * 16 + l15;                                \
      _Pragma("unroll") for (int ks = 0; ks < 2; ++ks)                                     \
        af[mi][ks] = *(const bf16x8*)((BUF) + row * 64 + (((ks * 4 + lg) ^ swz) << 3)); }

#define PHASE_MFMA(Q)                                                                      \
    __builtin_amdgcn_s_setprio(1);                                                         \
    _Pragma("unroll") for (int mi = 0; mi < 2; ++mi)                                       \
    _Pragma("unroll") for (int nt = 0; nt < 3; ++nt)                                       \
    _Pragma("unroll") for (int ks = 0; ks < 2; ++ks)                                       \
      acc[(Q) * 2 + mi][nt] = __builtin_amdgcn_mfma_f32_16x16x32_bf16(                     \
          af[mi][ks], bfr[nt][ks], acc[(Q) * 2 + mi][nt], 0, 0, 0);                        \
    __builtin_amdgcn_s_setprio(0);

  // ---- prologue: tile 0, one-time full drain ----
  STAGE_B(B0s, 0, 0); STAGE_B(B0s, 0, 1); STAGE_B(B0s, 0, 2);
  STAGE_A(A0s, 0, 0); STAGE_A(A0s, 0, 2); STAGE_A(A0s, 0, 1); STAGE_A(A0s, 0, 3);
  asm volatile("s_waitcnt vmcnt(0)" ::: "memory");
  __builtin_amdgcn_s_barrier();
  asm volatile("" ::: "memory");

  const int NT = DMODEL / 64;   // 16 K-tiles
  for (int t = 0; t < NT; ++t) {
    const bool stg = (t + 1 < NT);
    short* const Ac = (t & 1) ? A1s : A0s;
    short* const Bc = (t & 1) ? B1s : B0s;
    short* const An = (t & 1) ? A0s : A1s;
    short* const Bn = (t & 1) ? B0s : B1s;
    const int kn = (t + 1) * 64;

    bf16x8 af[2][2], bfr[3][2];

    // ---- P1: read B all + A m0,m1; stage B(t+1) x3 ----
#pragma unroll
    for (int nt = 0; nt < 3; ++nt) {
      const int row = wc * 48 + nt * 16 + l15;
#pragma unroll
      for (int ks = 0; ks < 2; ++ks)
        bfr[nt][ks] = *(const bf16x8*)(Bc + row * 64 + (((ks * 4 + lg) ^ swz) << 3));
    }
    PHASE_READ_A(Ac, 0);
    if (stg) { STAGE_B(Bn, kn, 0); STAGE_B(Bn, kn, 1); STAGE_B(Bn, kn, 2); }
    PHASE_BAR();
    PHASE_MFMA(0);
    PHASE_BAR();

    // ---- P2: read A m2,m3; stage A(t+1) op0,op2 ----
    PHASE_READ_A(Ac, 1);
    if (stg) { STAGE_A(An, kn, 0); STAGE_A(An, kn, 2); }
    PHASE_BAR();
    PHASE_MFMA(1);
    if (stg) { asm volatile("s_waitcnt vmcnt(5)" ::: "memory"); }
    else     { asm volatile("s_waitcnt vmcnt(0)" ::: "memory"); }
    PHASE_BAR();

    // ---- P3: read A m4,m5; stage A(t+1) op1,op3 ----
    PHASE_READ_A(Ac, 2);
    if (stg) { STAGE_A(An, kn, 1); STAGE_A(An, kn, 3); }
    PHASE_BAR();
    PHASE_MFMA(2);
    PHASE_BAR();

    // ---- P4: read A m6,m7; no stage ----
    PHASE_READ_A(Ac, 3);
    PHASE_BAR();
    PHASE_MFMA(3);
    if (stg) { asm volatile("s_waitcnt vmcnt(2)" ::: "memory"); }
    else     { asm volatile("s_waitcnt vmcnt(0)" ::: "memory"); }
    PHASE_BAR();
  }
#undef STAGE_A
#undef STAGE_B
#undef PHASE_BAR
#undef PHASE_READ_A
#undef PHASE_MFMA

  // ---- epilogue: scatter to q / k / v ----
#pragma unroll
  for (int mf = 0; mf < 8; ++mf) {
    const int rowb = m0 + wr * 128 + mf * 16 + lg * 4;
#pragma unroll
    for (int r4 = 0; r4 < 4; ++r4) {
      const int row = rowb + r4;
      const int slot = slot_map[row];
#pragma unroll
      for (int nt = 0; nt < 3; ++nt) {
        const int col = n0 + wc * 48 + nt * 16 + l15;
        const short bv = f2bf(acc[mf][nt][r4]);
        if (col < DMODEL)
          qbuf[(size_t)row * DMODEL + col] = bv;
        else if (col < 2 * DMODEL)
          kcache[(size_t)slot * DMODEL + (col - DMODEL)] = bv;
        else
          vcache[(size_t)slot * DMODEL + (col - 2 * DMODEL)] = bv;
      }
    }
  }
}

// ---------------- out-proj GEMM: 128x128 tile, BK=64, 4 waves (2x2), counted-vmcnt dbuf ----
// Square wave grid halves LDS-read redundancy (A x2 + B x2 vs A x4 + B x1): 30 B/KFLOP.
// Grid (32,8)=256 blocks, 64 KiB dyn LDS -> 2 blocks/CU. vmcnt(8): tile t's 8 ops retired,
// t+1's 8 stay in flight across the barrier.
__global__ __launch_bounds__(256, 2) void gemm1_kernel(
    const short* __restrict__ A, const short* __restrict__ W,
    float* __restrict__ outf)
{
  extern __shared__ short smem1[];   // 32768 shorts = 64 KiB

  const int m0 = blockIdx.x * 128;
  const int n0 = blockIdx.y * 128;
  const short* Ag = A + (size_t)m0 * DMODEL;
  const short* Bg = W + (size_t)n0 * DMODEL;

  const int tid = threadIdx.x;
  const int wave = tid >> 6, lane = tid & 63;
  const int l15 = lane & 15, lg = lane >> 4;
  const int wr = wave >> 1, wc = wave & 1;   // wave tile 64 x 64
  const int swz = l15 & 7;

  short* const As0 = smem1;           // [128][64]
  short* const Bs0 = smem1 + 8192;
  short* const As1 = smem1 + 16384;
  short* const Bs1 = smem1 + 24576;

  f32x4 acc[4][4];
#pragma unroll
  for (int m = 0; m < 4; m++)
#pragma unroll
    for (int n = 0; n < 4; n++) acc[m][n] = (f32x4)0.f;

#define STG1(LA, LB, K0) {                                                                 \
    _Pragma("unroll") for (int p = 0; p < 4; ++p) {                                        \
      const int u = p * 256 + tid; const int r = u >> 3; const int cs = (u & 7) ^ (r & 7); \
      __builtin_amdgcn_global_load_lds((g_void_t*)(Ag + (size_t)r * DMODEL + (K0) + cs * 8), \
          (lds_void_t*)((LA) + (p * 256 + wave * 64) * 8), 16, 0, 0); }                    \
    _Pragma("unroll") for (int p = 0; p < 4; ++p) {                                        \
      const int u = p * 256 + tid; const int r = u >> 3; const int cs = (u & 7) ^ (r & 7); \
      __builtin_amdgcn_global_load_lds((g_void_t*)(Bg + (size_t)r * DMODEL + (K0) + cs * 8), \
          (lds_void_t*)((LB) + (p * 256 + wave * 64) * 8), 16, 0, 0); } }

  STG1(As0, Bs0, 0);
  asm volatile("s_waitcnt vmcnt(0)" ::: "memory");
  __builtin_amdgcn_s_barrier();
  asm volatile("" ::: "memory");

  for (int t = 0; t < 16; ++t) {
    const int cur = t & 1;
    short* const Ac = cur ? As1 : As0;
    short* const Bc = cur ? Bs1 : Bs0;
    short* const An = cur ? As0 : As1;
    short* const Bn = cur ? Bs0 : Bs1;
    if (t + 1 < 16) {
      STG1(An, Bn, (t + 1) * 64);
      asm volatile("s_waitcnt vmcnt(8)" ::: "memory");   // tile t retired; t+1's 8 in flight
    } else {
      asm volatile("s_waitcnt vmcnt(0)" ::: "memory");
    }
    asm volatile("" ::: "memory");
    __builtin_amdgcn_s_barrier();
    asm volatile("" ::: "memory");

    bf16x8 af[4][2], bfr[4][2];
#pragma unroll
    for (int m4 = 0; m4 < 4; ++m4) {
      const int row = wr * 64 + m4 * 16 + l15;
#pragma unroll
      for (int ks = 0; ks < 2; ++ks)
        af[m4][ks] = *(const bf16x8*)(Ac + row * 64 + (((ks * 4 + lg) ^ swz) << 3));
    }
#pragma unroll
    for (int n4 = 0; n4 < 4; ++n4) {
      const int row = wc * 64 + n4 * 16 + l15;
#pragma unroll
      for (int ks = 0; ks < 2; ++ks)
        bfr[n4][ks] = *(const bf16x8*)(Bc + row * 64 + (((ks * 4 + lg) ^ swz) << 3));
    }
    __builtin_amdgcn_s_setprio(1);
#pragma unroll
    for (int m4 = 0; m4 < 4; ++m4)
#pragma unroll
      for (int n4 = 0; n4 < 4; ++n4)
#pragma unroll
        for (int ks = 0; ks < 2; ++ks)
          acc[m4][n4] = __builtin_amdgcn_mfma_f32_16x16x32_bf16(af[m4][ks], bfr[n4][ks], acc[m4][n4], 0, 0, 0);
    __builtin_amdgcn_s_setprio(0);

    asm volatile("" ::: "memory");
    __builtin_amdgcn_s_barrier();
    asm volatile("" ::: "memory");
  }
#undef STG1

#pragma unroll
  for (int m4 = 0; m4 < 4; ++m4) {
    const int rowb = m0 + wr * 64 + m4 * 16 + lg * 4;
#pragma unroll
    for (int n4 = 0; n4 < 4; ++n4) {
      const int col = n0 + wc * 64 + n4 * 16 + l15;
#pragma unroll
      for (int r4 = 0; r4 < 4; ++r4)
        outf[(size_t)(rowb + r4) * DMODEL + col] = acc[m4][n4][r4];
    }
  }
}

// ---------------- sliding-window flash attention (round-6 proven config) ----------------
// grid: (S/128, H, B), block 512 (8 waves), wave owns 16 q-rows.
// Fixed-shift softmax (p = exp(s - 12)); register-prefetched K/V staging one tile ahead.
// Balance flip: bz==1 reverses bx so co-resident blocks pair light+heavy q-tiles.
__global__ __launch_bounds__(512, 4) void attn_kernel(
    const short* __restrict__ qbuf,
    const short* __restrict__ kcache, const short* __restrict__ vcache,
    const int* __restrict__ block_tables, const int* __restrict__ context_lens,
    const int* __restrict__ window_size,
    short* __restrict__ attn_out)
{
  __shared__ short Ks[KT * 64];        // XOR-swizzled rows (row stride 128B)
  __shared__ short Vt[HDIM * VP];      // V^T, key-rotated within rows, stride 72
  __shared__ short Pb[8 * 16 * VP];    // per-wave P tiles, stride 72

  const int b = blockIdx.z, h = blockIdx.y;
  const int bx = (b & 1) ? ((int)gridDim.x - 1 - (int)blockIdx.x) : (int)blockIdx.x;
  const int q0 = bx * 128;
  const int ctx = context_lens[b];
  const int ws  = window_size[0];
  const int* bt = block_tables + b * NBLK;

  const int tid  = threadIdx.x;
  const int wave = tid >> 6, lane = tid & 63;
  const int l15 = lane & 15, lg = lane >> 4;
  const int qw = q0 + wave * 16;       // this wave's 16 q-rows

  const short* qp = qbuf + ((size_t)(b * S_LEN + qw + l15)) * DMODEL + h * HDIM;
  const bf16x8 qf0 = *(const bf16x8*)(qp + lg * 8);
  const bf16x8 qf1 = *(const bf16x8*)(qp + 32 + lg * 8);

  f32x4 oacc[4];
  float lrow[4];
#pragma unroll
  for (int i = 0; i < 4; i++) { oacc[i] = (f32x4)0.f; lrow[i] = 0.f; }

  int kstart = q0 - ws + 1; if (kstart < 0) kstart = 0; kstart &= ~(KT - 1);
  int kend = q0 + 128; if (kend > ctx) kend = ctx;

  const int kr = tid >> 3;             // staging: tile-local key 0..63
  const int dc = (tid & 7) << 3;       // staging: d-chunk
  const float rscale = 0.125f;         // HD^-0.5
  const float FM = 12.f;               // fixed softmax shift
  short* pw = Pb + wave * (16 * VP);
  const int swz = (l15 & 7) << 4;

  bf16x8 kreg = (bf16x8)0, vreg = (bf16x8)0;
  {
    const int key = kstart + kr;
    if (key < ctx) {
      const int slot = bt[key >> 4] * 16 + (key & 15);
      kreg = *(const bf16x8*)(kcache + (size_t)slot * DMODEL + h * HDIM + dc);
      vreg = *(const bf16x8*)(vcache + (size_t)slot * DMODEL + h * HDIM + dc);
    }
  }

  for (int kt = kstart; kt < kend; kt += KT) {
    __syncthreads();
    *(bf16x8*)((char*)Ks + kr * 128 + ((dc * 2) ^ ((kr & 7) << 4))) = kreg;
    const int vcol = (kr + dc) & 63;
#pragma unroll
    for (int j = 0; j < 8; j++) Vt[(dc + j) * VP + vcol] = vreg[j];
    kreg = (bf16x8)0; vreg = (bf16x8)0;
    if (kt + KT < kend) {
      const int key = kt + KT + kr;
      if (key < ctx) {
        const int slot = bt[key >> 4] * 16 + (key & 15);
        kreg = *(const bf16x8*)(kcache + (size_t)slot * DMODEL + h * HDIM + dc);
        vreg = *(const bf16x8*)(vcache + (size_t)slot * DMODEL + h * HDIM + dc);
      }
    }
    __syncthreads();

    if ((kt > qw + 15) || (kt + (KT - 1) <= qw - ws)) continue;

    f32x4 sacc[4];
#pragma unroll
    for (int cg = 0; cg < 4; cg++) sacc[cg] = (f32x4)0.f;
#pragma unroll
    for (int cg = 0; cg < 4; cg++) {
      const char* kp = (const char*)Ks + (cg * 16 + l15) * 128;
      const bf16x8 k0 = *(const bf16x8*)(kp + ((lg * 16) ^ swz));
      const bf16x8 k1 = *(const bf16x8*)(kp + ((64 + lg * 16) ^ swz));
      sacc[cg] = __builtin_amdgcn_mfma_f32_16x16x32_bf16(qf0, k0, sacc[cg], 0, 0, 0);
      sacc[cg] = __builtin_amdgcn_mfma_f32_16x16x32_bf16(qf1, k1, sacc[cg], 0, 0, 0);
    }

    const bool fullvis = (kt + (KT - 1) <= qw) && (qw + 15 - kt < ws) && (kt + (KT - 1) < ctx);

    if (fullvis) {
#pragma unroll
      for (int r = 0; r < 4; r++) {
        const float e0 = __expf(sacc[0][r] * rscale - FM);
        const float e1 = __expf(sacc[1][r] * rscale - FM);
        const float e2 = __expf(sacc[2][r] * rscale - FM);
        const float e3 = __expf(sacc[3][r] * rscale - FM);
        lrow[r] += (e0 + e1) + (e2 + e3);
        short* pr = pw + (lg * 4 + r) * VP + l15;
        pr[0]  = f2bf(e0); pr[16] = f2bf(e1);
        pr[32] = f2bf(e2); pr[48] = f2bf(e3);
      }
    } else {
#pragma unroll
      for (int r = 0; r < 4; r++) {
        const int qrow = qw + lg * 4 + r;
        const int key0 = kt + l15;
        const bool ok0 = (key0      <= qrow) && (qrow - key0      < ws) && (key0      < ctx);
        const bool ok1 = (key0 + 16 <= qrow) && (qrow - key0 - 16 < ws) && (key0 + 16 < ctx);
        const bool ok2 = (key0 + 32 <= qrow) && (qrow - key0 - 32 < ws) && (key0 + 32 < ctx);
        const bool ok3 = (key0 + 48 <= qrow) && (qrow - key0 - 48 < ws) && (key0 + 48 < ctx);
        const float e0 = ok0 ? __expf(sacc[0][r] * rscale - FM) : 0.f;
        const float e1 = ok1 ? __expf(sacc[1][r] * rscale - FM) : 0.f;
        const float e2 = ok2 ? __expf(sacc[2][r] * rscale - FM) : 0.f;
        const float e3 = ok3 ? __expf(sacc[3][r] * rscale - FM) : 0.f;
        lrow[r] += (e0 + e1) + (e2 + e3);
        short* pr = pw + (lg * 4 + r) * VP + l15;
        pr[0]  = f2bf(e0); pr[16] = f2bf(e1);
        pr[32] = f2bf(e2); pr[48] = f2bf(e3);
      }
    }

    asm volatile("s_waitcnt lgkmcnt(0)" ::: "memory");

#pragma unroll
    for (int kk = 0; kk < 2; kk++) {
      const bf16x8 pa = *(const bf16x8*)(pw + l15 * VP + kk * 32 + lg * 8);
#pragma unroll
      for (int dn = 0; dn < 4; dn++) {
        const int vrow = dn * 16 + l15;
        const int roff = (kk * 32 + lg * 8 + (vrow & ~7)) & 63;
        const bf16x8 vb = *(const bf16x8*)(Vt + vrow * VP + roff);
        oacc[dn] = __builtin_amdgcn_mfma_f32_16x16x32_bf16(pa, vb, oacc[dn], 0, 0, 0);
      }
    }
  }

#pragma unroll
  for (int r = 0; r < 4; r++) {
    float ls = lrow[r];
    ls += __shfl_xor(ls, 1); ls += __shfl_xor(ls, 2);
    ls += __shfl_xor(ls, 4); ls += __shfl_xor(ls, 8);
    const float inv = 1.f / fmaxf(ls, 1e-30f);
    const int row = qw + lg * 4 + r;
    short* op = attn_out + ((size_t)(b * S_LEN + row)) * DMODEL + h * HDIM;
#pragma unroll
    for (int dn = 0; dn < 4; dn++)
      op[dn * 16 + l15] = f2bf(oacc[dn][r] * inv);
  }
}

// ---------------- launch ----------------
extern "C" void kernel_launch(void* const* d_in, const int* in_sizes, int n_in,
                              void* d_out, int out_size, void* d_ws, size_t ws_size,
                              hipStream_t stream) {
  const float* x  = (const float*)d_in[0];
  const float* wq = (const float*)d_in[1];
  const float* wk = (const float*)d_in[2];
  const float* wv = (const float*)d_in[3];
  const float* wo = (const float*)d_in[4];
  const int* block_tables = (const int*)d_in[5];
  const int* slot_mapping = (const int*)d_in[6];
  const int* context_lens = (const int*)d_in[7];
  const int* window_size  = (const int*)d_in[8];
  float* out = (float*)d_out;

  char* ws = (char*)d_ws;
  short* xb     = (short*)(ws + (size_t)( 0 << 20));
  short* wqb    = (short*)(ws + (size_t)( 8 << 20));
  short* wkb    = (short*)(ws + (size_t)(10 << 20));
  short* wvb    = (short*)(ws + (size_t)(12 << 20));
  short* wob    = (short*)(ws + (size_t)(14 << 20));
  short* qbuf   = (short*)(ws + (size_t)(16 << 20));
  short* kcache = (short*)(ws + (size_t)(24 << 20));
  short* vcache = (short*)(ws + (size_t)(32 << 20));
  short* abuf   = (short*)(ws + (size_t)(40 << 20));

  // one-time: allow dynamic LDS (host state calls, not stream-captured)
  static bool ginit = [] {
    hipFuncSetAttribute(reinterpret_cast<const void*>(&gemm8_kernel),
                        hipFuncAttributeMaxDynamicSharedMemorySize, 114688);
    hipFuncSetAttribute(reinterpret_cast<const void*>(&gemm1_kernel),
                        hipFuncAttributeMaxDynamicSharedMemorySize, 65536);
    return true;
  }();
  (void)ginit;

  cvt_all_kernel<<<4096, 256, 0, stream>>>(x, wq, wk, wv, wo, xb, wqb, wkb, wvb, wob);

  gemm8_kernel<<<dim3(16, 16), 512, 114688, stream>>>(xb, wqb, wkb, wvb, slot_mapping,
                                                      qbuf, kcache, vcache);

  attn_kernel<<<dim3(S_LEN / 128, NHEAD, BATCH), 512, 0, stream>>>(
      qbuf, kcache, vcache, block_tables, context_lens, window_size, abuf);

  gemm1_kernel<<<dim3(32, 8), 256, 65536, stream>>>(abuf, wob, out);
}